// Round 4
// baseline (229.030 us; speedup 1.0000x reference)
//
#include <hip/hip_runtime.h>
#include <math.h>

// MoE top-2 router. Round 4: pipelined K-loop — x double-buffered in LDS via
// global_load_lds with manual fine-grained s_waitcnt vmcnt(20) + raw s_barrier
// (prefetch stays in flight across the barrier); W fragments loaded directly
// global->VGPR from pre-converted bf16 hi/lo (L2-resident). K-split partials
// in ws + reduce/softmax/top2 kernel.
//
// x: [16384, 2048] fp32, W: [64, 2048] fp32.
// outputs (concat, fp32): mask [T,64], idx-as-float [T,2],
//                         router_probs [T,64], probs [T,64]

#define D_DIM 2048
#define E_DIM 64

typedef __bf16 bf16x8 __attribute__((ext_vector_type(8)));
typedef unsigned short us8 __attribute__((ext_vector_type(8)));
typedef float f32x4 __attribute__((ext_vector_type(4)));

static __device__ __forceinline__ unsigned short f2bf(float f) {
    unsigned int u = __float_as_uint(f);
    u += 0x7fffu + ((u >> 16) & 1u);   // RNE
    return (unsigned short)(u >> 16);
}
static __device__ __forceinline__ float bf2f(unsigned short h) {
    return __uint_as_float(((unsigned int)h) << 16);
}
static __device__ __forceinline__ void split4(const float4 v, ushort4* h, ushort4* l) {
    h->x = f2bf(v.x); l->x = f2bf(v.x - bf2f(h->x));
    h->y = f2bf(v.y); l->y = f2bf(v.y - bf2f(h->y));
    h->z = f2bf(v.z); l->z = f2bf(v.z - bf2f(h->z));
    h->w = f2bf(v.w); l->w = f2bf(v.w - bf2f(h->w));
}

static __device__ __forceinline__ void gld_lds16(const void* g, void* l) {
    __builtin_amdgcn_global_load_lds(
        (const __attribute__((address_space(1))) unsigned int*)g,
        (__attribute__((address_space(3))) unsigned int*)l,
        16, 0, 0);
}

// ---- pre-convert W (64x2048 fp32) -> bf16 hi/lo, linear layout ----
__global__ __launch_bounds__(256, 1) void convert_w(
    const float4* __restrict__ W4, unsigned short* __restrict__ WH,
    unsigned short* __restrict__ WL)
{
    int i = blockIdx.x * 256 + threadIdx.x;   // float4 index
    float4 v = W4[i];
    ushort4 h, l;
    split4(v, &h, &l);
    *(ushort4*)&WH[i * 4] = h;
    *(ushort4*)&WL[i * 4] = l;
}

// ---- GEMM: block = 64 tokens x K-slice (2048/KS); partials to P ----
template<int KS>
__global__ __launch_bounds__(256, 3) void gemm_part(
    const float* __restrict__ x,
    const unsigned short* __restrict__ WHg, const unsigned short* __restrict__ WLg,
    float* __restrict__ P, int T)
{
    // double-buffered, 16B-slot-XOR-swizzled x tile (fp32)
    __shared__ __align__(16) float XF[2][64 * 64];   // 32 KB

    const int tid  = threadIdx.x;
    const int lane = tid & 63;
    const int wv   = tid >> 6;
    const int quad = lane >> 4;
    const int l16  = lane & 15;

    const int ntb = T >> 6;
    const int tb  = blockIdx.x % ntb;
    const int ksl = blockIdx.x / ntb;
    const int t0  = tb << 6;
    const int NCH = (D_DIM / KS) >> 6;        // 64-k chunks per slice (pow2)
    const int k0  = ksl * (D_DIM / KS);

    f32x4 acc[4];
    #pragma unroll
    for (int n = 0; n < 4; ++n) { f32x4 z = {0.f, 0.f, 0.f, 0.f}; acc[n] = z; }

    // staging-lane constants: 4 gld_lds16 per wave per chunk
    const int srow = wv * 4 + (lane >> 4);    // + 16*i -> x row in tile
    const int scg  = lane & 15;               // float4 col before swizzle

    // prologue: stage chunk 0 into buf 0  (4 vmem per wave)
    #pragma unroll
    for (int i = 0; i < 4; ++i) {
        int row = i * 16 + srow;
        int cg  = scg ^ (row & 15);
        gld_lds16(x + (size_t)(t0 + row) * D_DIM + k0 + cg * 4,
                  &XF[0][(i * 256 + wv * 64) * 4]);
    }

    for (int ch = 0; ch < NCH; ++ch) {
        const int buf = ch & 1;
        const int kc  = k0 + (ch << 6);

        // (a) W fragments for this chunk: global (L2) -> regs, 16 x 16B loads
        bf16x8 bh[2][4], bl[2][4];
        #pragma unroll
        for (int ks2 = 0; ks2 < 2; ++ks2)
            #pragma unroll
            for (int n = 0; n < 4; ++n) {
                const size_t wo = (size_t)(n * 16 + l16) * D_DIM + kc + ks2 * 32 + quad * 8;
                bh[ks2][n] = *(const bf16x8*)(WHg + wo);
                bl[ks2][n] = *(const bf16x8*)(WLg + wo);
            }

        // (b) prefetch next chunk's x into the other buffer (uniform count:
        //     last iteration wraps to chunk 0, data unused)
        {
            const int chn = (ch + 1) & (NCH - 1);
            const int kcn = k0 + (chn << 6);
            #pragma unroll
            for (int i = 0; i < 4; ++i) {
                int row = i * 16 + srow;
                int cg  = scg ^ (row & 15);
                gld_lds16(x + (size_t)(t0 + row) * D_DIM + kcn + cg * 4,
                          &XF[buf ^ 1][(i * 256 + wv * 64) * 4]);
            }
        }

        // (c) drain ONLY the 4 oldest vmem ops (= this chunk's x glds);
        //     16 W loads + 4 prefetch glds stay in flight across the barrier
        asm volatile("s_waitcnt vmcnt(20)" ::: "memory");
        __builtin_amdgcn_s_barrier();

        // (d) compute: 2 k-steps of 32, split-bf16 3-term MFMA
        #pragma unroll
        for (int ks2 = 0; ks2 < 2; ++ks2) {
            const int tr = wv * 16 + l16;
            const int c0 = ks2 * 8 + quad * 2;
            float4 xa = *(const float4*)&XF[buf][(tr * 16 + ( c0      ^ (tr & 15))) * 4];
            float4 xb = *(const float4*)&XF[buf][(tr * 16 + ((c0 + 1) ^ (tr & 15))) * 4];
            ushort4 h0, l0, h1, l1;
            split4(xa, &h0, &l0);
            split4(xb, &h1, &l1);
            union { us8 u; bf16x8 b; } ua, ul;
            ua.u = (us8){h0.x, h0.y, h0.z, h0.w, h1.x, h1.y, h1.z, h1.w};
            ul.u = (us8){l0.x, l0.y, l0.z, l0.w, l1.x, l1.y, l1.z, l1.w};

            #pragma unroll
            for (int n = 0; n < 4; ++n) {
                acc[n] = __builtin_amdgcn_mfma_f32_16x16x32_bf16(ua.b, bh[ks2][n], acc[n], 0, 0, 0);
                acc[n] = __builtin_amdgcn_mfma_f32_16x16x32_bf16(ul.b, bh[ks2][n], acc[n], 0, 0, 0);
                acc[n] = __builtin_amdgcn_mfma_f32_16x16x32_bf16(ua.b, bl[ks2][n], acc[n], 0, 0, 0);
            }
        }

        // (e) all waves done reading XF[buf] before next iter overwrites it
        __builtin_amdgcn_s_barrier();
    }

    // ---- write partial logits: P[ksl][t][e] ----
    float* Pb = P + ((size_t)ksl * T + t0) * 64;
    #pragma unroll
    for (int n = 0; n < 4; ++n)
        #pragma unroll
        for (int r = 0; r < 4; ++r)
            Pb[(wv * 16 + quad * 4 + r) * 64 + n * 16 + l16] = acc[n][r];
}

// ---- reduce partials + softmax + top-2 + outputs; wave per 4 tokens ----
template<int KS>
__global__ __launch_bounds__(256, 4) void reduce_router(
    const float* __restrict__ P, int T,
    float* __restrict__ mask_out, float* __restrict__ idx_out,
    float* __restrict__ rp_out, float* __restrict__ probs_out)
{
    const int tid  = threadIdx.x;
    const int lane = tid & 63;
    const int wv   = tid >> 6;

    for (int i = 0; i < 4; ++i) {
        int t = blockIdx.x * 16 + wv * 4 + i;
        float v = 0.f;
        #pragma unroll
        for (int s = 0; s < KS; ++s)
            v += P[((size_t)s * T + t) * 64 + lane];

        // argmax, lower-index tie-break (matches jax.lax.top_k)
        float bv = v; int bi = lane;
        #pragma unroll
        for (int off = 1; off < 64; off <<= 1) {
            float ov = __shfl_xor(bv, off, 64);
            int   oi = __shfl_xor(bi, off, 64);
            bool take = (ov > bv) || (ov == bv && oi < bi);
            bv = take ? ov : bv;
            bi = take ? oi : bi;
        }
        float m = bv; int i1 = bi;

        float p = __expf(v - m);
        float s = p;
        #pragma unroll
        for (int off = 1; off < 64; off <<= 1) s += __shfl_xor(s, off, 64);
        float prob = p / s;

        float v2 = (lane == i1) ? -INFINITY : v;
        float bv2 = v2; int bi2 = lane;
        #pragma unroll
        for (int off = 1; off < 64; off <<= 1) {
            float ov = __shfl_xor(bv2, off, 64);
            int   oi = __shfl_xor(bi2, off, 64);
            bool take = (ov > bv2) || (ov == bv2 && oi < bi2);
            bv2 = take ? ov : bv2;
            bi2 = take ? oi : bi2;
        }
        int i2 = bi2;

        float pd = __shfl(prob, i1, 64) + __shfl(prob, i2, 64);
        bool top = (lane == i1) || (lane == i2);

        mask_out[(size_t)t * 64 + lane]  = top ? 1.f : 0.f;
        rp_out[(size_t)t * 64 + lane]    = top ? prob / pd : 0.f;
        probs_out[(size_t)t * 64 + lane] = prob;
        if (lane == 0) {
            idx_out[(size_t)t * 2]     = (float)i1;
            idx_out[(size_t)t * 2 + 1] = (float)i2;
        }
    }
}

extern "C" void kernel_launch(void* const* d_in, const int* in_sizes, int n_in,
                              void* d_out, int out_size, void* d_ws, size_t ws_size,
                              hipStream_t stream) {
    const float* x = (const float*)d_in[0];
    const float* W = (const float*)d_in[1];
    float* out = (float*)d_out;

    const int T  = in_sizes[0] / D_DIM;     // 16384 tokens
    const int WN = in_sizes[1];             // 131072 elements

    unsigned short* WH = (unsigned short*)d_ws;
    unsigned short* WL = WH + WN;
    float* P = (float*)(WL + WN);           // partials after 512 KB of W

    float* mask_out  = out;
    float* idx_out   = out + (size_t)T * E_DIM;
    float* rp_out    = idx_out + (size_t)T * 2;
    float* probs_out = rp_out + (size_t)T * E_DIM;

    const size_t avail = ws_size - (size_t)WN * 4;
    const size_t slice_bytes = (size_t)T * 64 * 4;

    convert_w<<<dim3(WN / 1024), dim3(256), 0, stream>>>((const float4*)W, WH, WL);

    if (avail >= 4 * slice_bytes) {
        gemm_part<4><<<dim3((T / 64) * 4), dim3(256), 0, stream>>>(x, WH, WL, P, T);
        reduce_router<4><<<dim3(T / 16), dim3(256), 0, stream>>>(
            P, T, mask_out, idx_out, rp_out, probs_out);
    } else if (avail >= 2 * slice_bytes) {
        gemm_part<2><<<dim3((T / 64) * 2), dim3(256), 0, stream>>>(x, WH, WL, P, T);
        reduce_router<2><<<dim3(T / 16), dim3(256), 0, stream>>>(
            P, T, mask_out, idx_out, rp_out, probs_out);
    } else {
        gemm_part<1><<<dim3(T / 64), dim3(256), 0, stream>>>(x, WH, WL, P, T);
        reduce_router<1><<<dim3(T / 16), dim3(256), 0, stream>>>(
            P, T, mask_out, idx_out, rp_out, probs_out);
    }
}

// Round 5
// 210.044 us; speedup vs baseline: 1.0904x; 1.0904x over previous
//
#include <hip/hip_runtime.h>
#include <math.h>

// MoE top-2 router. Round 5: single-wave blocks (zero barriers), x staged
// through a wave-private LDS ring-4 via global_load_lds with window-exact
// manual s_waitcnt vmcnt(N); W pre-shuffled to MFMA-B-fragment order in ws
// so every W load is lane*16B (perfectly coalesced, L2-resident).
// KS=4 K-split, partials in ws, then reduce+softmax+top2 kernel.
//
// x: [16384, 2048] fp32, W: [64, 2048] fp32.
// outputs (concat, fp32): mask [T,64], idx-as-float [T,2],
//                         router_probs [T,64], probs [T,64]

#define D_DIM 2048
#define E_DIM 64
#define KS 4               // K-split
#define KSTEPS 16          // (D_DIM/KS)/32 k-steps per wave

typedef __bf16 bf16x8 __attribute__((ext_vector_type(8)));
typedef unsigned short us8 __attribute__((ext_vector_type(8)));
typedef float f32x4 __attribute__((ext_vector_type(4)));

#define FENCE asm volatile("" ::: "memory")

static __device__ __forceinline__ unsigned short f2bf(float f) {
    unsigned int u = __float_as_uint(f);
    u += 0x7fffu + ((u >> 16) & 1u);   // RNE
    return (unsigned short)(u >> 16);
}
static __device__ __forceinline__ float bf2f(unsigned short h) {
    return __uint_as_float(((unsigned int)h) << 16);
}
static __device__ __forceinline__ void split4(const float4 v, ushort4* h, ushort4* l) {
    h->x = f2bf(v.x); l->x = f2bf(v.x - bf2f(h->x));
    h->y = f2bf(v.y); l->y = f2bf(v.y - bf2f(h->y));
    h->z = f2bf(v.z); l->z = f2bf(v.z - bf2f(h->z));
    h->w = f2bf(v.w); l->w = f2bf(v.w - bf2f(h->w));
}

static __device__ __forceinline__ void gld_lds16(const void* g, void* l) {
    __builtin_amdgcn_global_load_lds(
        (const __attribute__((address_space(1))) unsigned int*)g,
        (__attribute__((address_space(3))) unsigned int*)l,
        16, 0, 0);
}

// ---- convert W -> MFMA-B-fragment order, bf16 hi/lo ----
// WB layout (16B units): [sg=0..63][n=0..3][h=0..1][lane=0..63]
//   fragment for lane (l16,quad): B[e = n*16+l16][k = sg*32 + quad*8 .. +7]
__global__ __launch_bounds__(256, 1) void convert_w(
    const float* __restrict__ W, unsigned short* __restrict__ WB)
{
    int u = blockIdx.x * 256 + threadIdx.x;     // 32768 outputs of 16B
    int lane = u & 63;
    int r = u >> 6;
    int h = r & 1;  r >>= 1;
    int n = r & 3;  int sg = r >> 2;
    int E  = n * 16 + (lane & 15);
    int k0 = sg * 32 + (lane >> 4) * 8;
    const float4* src = (const float4*)(W + (size_t)E * D_DIM + k0);
    float4 a = src[0], b = src[1];
    ushort4 ha, la, hb, lb;
    split4(a, &ha, &la);
    split4(b, &hb, &lb);
    us8 out = h ? (us8){la.x, la.y, la.z, la.w, lb.x, lb.y, lb.z, lb.w}
                : (us8){ha.x, ha.y, ha.z, ha.w, hb.x, hb.y, hb.z, hb.w};
    *(us8*)(WB + (size_t)u * 8) = out;
}

// ---- GEMM: 1 wave per block, 32 tokens x 64 experts x K-slice 512 ----
__global__ __launch_bounds__(64, 2) void gemm_part(
    const float* __restrict__ x, const unsigned short* __restrict__ WB,
    float* __restrict__ P, int T)
{
    __shared__ __align__(16) float RING[4][1024];   // 16 KB: 4 k-step buffers

    const int lane = threadIdx.x;
    const int quad = lane >> 4;
    const int l16  = lane & 15;

    const int ntb = T >> 5;                 // 32-token tiles
    const int tb  = blockIdx.x % ntb;
    const int ksl = blockIdx.x / ntb;
    const int t0  = tb << 5;
    const int kb  = ksl * (D_DIM / KS);     // k base of slice

    // x staging lane constants (slot-swizzled on the GLOBAL side):
    // instr j: group g=j>>1 (tokens g*16..+15), half jj=j&1 (k 0-15 / 16-31)
    // lane i -> row g*16 + (i>>2), float4-col cg = (i&3) ^ ((i>>3)&3)
    const int srow = lane >> 2;
    const int scg  = (lane & 3) ^ ((lane >> 3) & 3);

    f32x4 acc[2][4];
    #pragma unroll
    for (int g = 0; g < 2; ++g)
        #pragma unroll
        for (int n = 0; n < 4; ++n) { f32x4 z = {0.f, 0.f, 0.f, 0.f}; acc[g][n] = z; }

    // issue one k-step's x staging (4 gld_lds of 1KB each)
    auto stage = [&](int s) {
        const int kc = kb + s * 32;
        #pragma unroll
        for (int j = 0; j < 4; ++j) {
            int g = j >> 1, jj = j & 1;
            int row = g * 16 + (srow & 3) + ((srow >> 2) << 2);   // = g*16 + srow
            gld_lds16(x + (size_t)(t0 + row) * D_DIM + kc + jj * 16 + scg * 4,
                      &RING[s & 3][j * 256]);
        }
    };

    // load one k-step's W fragments (8 x 16B, lane-coalesced from L2)
    auto loadW = [&](int s, bf16x8 Wf[4][2]) {
        const int sg = ksl * KSTEPS + s;
        #pragma unroll
        for (int n = 0; n < 4; ++n)
            #pragma unroll
            for (int h = 0; h < 2; ++h)
                Wf[n][h] = *(const bf16x8*)(WB + ((((size_t)sg * 4 + n) * 2 + h) * 64 + lane) * 8);
    };

    // prologue (fenced so FIFO window arithmetic below is exact):
    bf16x8 Wc[4][2], Wn[4][2];
    stage(0);  FENCE;        // g0 (4)
    loadW(0, Wc); FENCE;     // W0 (8)
    stage(1);  FENCE;        // g1 (4)
    stage(2);  FENCE;        // g2 (4)

    const float fsw = 0.f; (void)fsw;

    #pragma unroll
    for (int s = 0; s < KSTEPS; ++s) {
        // window s issues: W_{s+1} (8) then gld_{s+3} (4)
        if (s + 1 < KSTEPS) loadW(s + 1, Wn);
        if (s + 3 < KSTEPS) stage(s + 3);

        // wait for buffer s only (window-exact; over-drain at tail is safe):
        // after-g0 = 28, after-g1 = 28, steady = 36, tail min = 16
        if (s < 2)            asm volatile("s_waitcnt vmcnt(28)" ::: "memory");
        else if (s < KSTEPS - 3) asm volatile("s_waitcnt vmcnt(36)" ::: "memory");
        else                  asm volatile("s_waitcnt vmcnt(16)" ::: "memory");

        // fragment reads from ring buffer s (bank-balanced via write swizzle)
        const int f = (l16 >> 1) & 3;
        const int jj = quad >> 1;
        const int c  = (2 * quad) & 3;
        #pragma unroll
        for (int g = 0; g < 2; ++g) {
            const float* B = &RING[s & 3][g * 512 + jj * 256];
            float4 xa = *(const float4*)&B[(l16 * 4 + ( c      ^ f)) * 4];
            float4 xb = *(const float4*)&B[(l16 * 4 + ((c + 1) ^ f)) * 4];
            ushort4 h0, l0, h1, l1;
            split4(xa, &h0, &l0);
            split4(xb, &h1, &l1);
            union { us8 u; bf16x8 b; } ua, ul;
            ua.u = (us8){h0.x, h0.y, h0.z, h0.w, h1.x, h1.y, h1.z, h1.w};
            ul.u = (us8){l0.x, l0.y, l0.z, l0.w, l1.x, l1.y, l1.z, l1.w};
            #pragma unroll
            for (int n = 0; n < 4; ++n) {
                acc[g][n] = __builtin_amdgcn_mfma_f32_16x16x32_bf16(ua.b, Wc[n][0], acc[g][n], 0, 0, 0);
                acc[g][n] = __builtin_amdgcn_mfma_f32_16x16x32_bf16(ul.b, Wc[n][0], acc[g][n], 0, 0, 0);
                acc[g][n] = __builtin_amdgcn_mfma_f32_16x16x32_bf16(ua.b, Wc[n][1], acc[g][n], 0, 0, 0);
            }
        }

        // rotate W registers
        #pragma unroll
        for (int n = 0; n < 4; ++n)
            #pragma unroll
            for (int h = 0; h < 2; ++h)
                Wc[n][h] = Wn[n][h];
    }

    // ---- write partial logits: P[ksl][t][e] ----
    float* Pb = P + ((size_t)ksl * T + t0) * 64;
    #pragma unroll
    for (int g = 0; g < 2; ++g)
        #pragma unroll
        for (int n = 0; n < 4; ++n)
            #pragma unroll
            for (int r = 0; r < 4; ++r)
                Pb[(g * 16 + quad * 4 + r) * 64 + n * 16 + l16] = acc[g][n][r];
}

// ---- reduce partials + softmax + top-2 + outputs; wave per 4 tokens ----
__global__ __launch_bounds__(256, 4) void reduce_router(
    const float* __restrict__ P, int T,
    float* __restrict__ mask_out, float* __restrict__ idx_out,
    float* __restrict__ rp_out, float* __restrict__ probs_out)
{
    const int tid  = threadIdx.x;
    const int lane = tid & 63;
    const int wv   = tid >> 6;

    for (int i = 0; i < 4; ++i) {
        int t = blockIdx.x * 16 + wv * 4 + i;
        float v = 0.f;
        #pragma unroll
        for (int s = 0; s < KS; ++s)
            v += P[((size_t)s * T + t) * 64 + lane];

        // argmax, lower-index tie-break (matches jax.lax.top_k)
        float bv = v; int bi = lane;
        #pragma unroll
        for (int off = 1; off < 64; off <<= 1) {
            float ov = __shfl_xor(bv, off, 64);
            int   oi = __shfl_xor(bi, off, 64);
            bool take = (ov > bv) || (ov == bv && oi < bi);
            bv = take ? ov : bv;
            bi = take ? oi : bi;
        }
        float m = bv; int i1 = bi;

        float p = __expf(v - m);
        float s = p;
        #pragma unroll
        for (int off = 1; off < 64; off <<= 1) s += __shfl_xor(s, off, 64);
        float prob = p / s;

        float v2 = (lane == i1) ? -INFINITY : v;
        float bv2 = v2; int bi2 = lane;
        #pragma unroll
        for (int off = 1; off < 64; off <<= 1) {
            float ov = __shfl_xor(bv2, off, 64);
            int   oi = __shfl_xor(bi2, off, 64);
            bool take = (ov > bv2) || (ov == bv2 && oi < bi2);
            bv2 = take ? ov : bv2;
            bi2 = take ? oi : bi2;
        }
        int i2 = bi2;

        float pd = __shfl(prob, i1, 64) + __shfl(prob, i2, 64);
        bool top = (lane == i1) || (lane == i2);

        mask_out[(size_t)t * 64 + lane]  = top ? 1.f : 0.f;
        rp_out[(size_t)t * 64 + lane]    = top ? prob / pd : 0.f;
        probs_out[(size_t)t * 64 + lane] = prob;
        if (lane == 0) {
            idx_out[(size_t)t * 2]     = (float)i1;
            idx_out[(size_t)t * 2 + 1] = (float)i2;
        }
    }
}

extern "C" void kernel_launch(void* const* d_in, const int* in_sizes, int n_in,
                              void* d_out, int out_size, void* d_ws, size_t ws_size,
                              hipStream_t stream) {
    const float* x = (const float*)d_in[0];
    const float* W = (const float*)d_in[1];
    float* out = (float*)d_out;

    const int T  = in_sizes[0] / D_DIM;     // 16384 tokens
    const int WN = in_sizes[1];             // 131072 elements

    unsigned short* WB = (unsigned short*)d_ws;         // 512 KB fragment-order W
    float* P = (float*)(WB + (size_t)WN * 2);           // KS partial slices

    float* mask_out  = out;
    float* idx_out   = out + (size_t)T * E_DIM;
    float* rp_out    = idx_out + (size_t)T * 2;
    float* probs_out = rp_out + (size_t)T * E_DIM;

    convert_w<<<dim3((WN * 2) / 8 / 256), dim3(256), 0, stream>>>(W, WB);
    gemm_part<<<dim3((T / 32) * KS), dim3(64), 0, stream>>>(x, WB, P, T);
    reduce_router<<<dim3(T / 16), dim3(256), 0, stream>>>(
        P, T, mask_out, idx_out, rp_out, probs_out);
}